// Round 6
// baseline (85.027 us; speedup 1.0000x reference)
//
#include <hip/hip_runtime.h>
#include <hip/hip_bf16.h>

#define NB 8
#define NT 4096
#define NC 128
#define NH 512
#define TB 64            // output time rows per block
#define MT 4             // output m-tiles (MT*16 == TB)
#define MTH 5            // staged h m-tiles (TB + 8 halo + pad -> 80 rows)

typedef __attribute__((ext_vector_type(8))) short bf16x8;
typedef __attribute__((ext_vector_type(4))) short bf16x4;
typedef __attribute__((ext_vector_type(4))) float f32x4;

__device__ __forceinline__ ushort f2bf(float f) {
    uint u = __float_as_uint(f);
    uint r = u + 0x7FFFu + ((u >> 16) & 1u);   // RNE
    return (ushort)(r >> 16);
}
__device__ __forceinline__ float bf2f(short b) {
    return __uint_as_float(((uint)(ushort)b) << 16);
}

// ---- Merged prep: weights + alphas to bf16, MFMA-fragment order ----
__global__ __launch_bounds__(512) void prep_all(
    const float* __restrict__ wb, const float* __restrict__ wres,
    const float* __restrict__ wskip, const float* __restrict__ a1,
    const float* __restrict__ a2, short* __restrict__ wbt,
    short* __restrict__ wct, short* __restrict__ a1t, short* __restrict__ a2t,
    int nalpha_blocks)
{
    int blk = blockIdx.x;
    if (blk < nalpha_blocks) {
        int g = blk * 512 + threadIdx.x;                 // [0, 1048576)
        const float* __restrict__ src = (g < 524288) ? a1 : a2;
        short* __restrict__ dst = (g < 524288) ? a1t : a2t;
        int o  = g & 524287;
        int l  = o & 63, jt = (o >> 6) & 31, tt = o >> 11;
        int t  = tt * 16 + ((l >> 4) << 2);
        int j  = jt * 16 + (l & 15);
        bf16x4 v;
        #pragma unroll
        for (int r = 0; r < 4; ++r) v[r] = (short)f2bf(src[(size_t)(t + r) * NH + j]);
        *reinterpret_cast<bf16x4*>(&dst[(size_t)o * 4]) = v;
    } else {
        int i = (blk - nalpha_blocks) * 512 + threadIdx.x;   // [0, 196608)
        if (i < 65536) {
            int ii = i & 7, l = (i >> 3) & 63, jt = (i >> 9) & 31, kt = i >> 14;
            int k = kt * 32 + (l >> 4) * 8 + ii;
            int j = jt * 16 + (l & 15);
            wbt[i] = (short)f2bf(wb[k * NH + j]);
        } else if (i < 65536 + 131072) {
            int i2 = i - 65536;
            int ii = i2 & 7, l = (i2 >> 3) & 63, jt = (i2 >> 9) & 15, kt = i2 >> 13;
            int k = kt * 32 + (l >> 4) * 8 + ii;
            int j = jt * 16 + (l & 15);
            float v = (j < 128) ? wres[k * NC + j] : wskip[k * NC + (j - 128)];
            wct[i2] = (short)f2bf(v);
        }
    }
}

// ---- Fused main kernel: 512 threads (8 waves), 64-row tile ----
// launch_bounds(512,2): cap 256 regs -> no spill (R3/R5 lesson: tighter caps spill acc1)
template<bool PACKED>
__global__ __launch_bounds__(512, 2) void conv1d_block_mfma(
    const float* __restrict__ x,      // (8,4096,128)
    const float* __restrict__ a1,     // (4096,512) f32 (fallback)
    const float* __restrict__ wd,     // (3,1,512)
    const float* __restrict__ a2,     // (4096,512) f32 (fallback)
    const short* __restrict__ wbt,
    const short* __restrict__ wct,
    const short* __restrict__ a1t,    // packed alphas (PACKED)
    const short* __restrict__ a2t,
    float* __restrict__ out)
{
    // A-frag layout: frag (mt,kt): lane l elem i = M[mt*16 + (l&15)][kt*32 + (l>>4)*8 + i]
    // union: xs (80x128 bf16 A-frags, 20 KB) then ys (64x512 bf16 A-frags, 64 KB)
    __shared__ short smem[MT * 16 * 64 * 8];   // 64 KB
    short* xs = smem;
    short* ys = smem;

    const int tid  = threadIdx.x;
    const int lane = tid & 63;
    const int wave = tid >> 6;          // 0..7
    const int b    = blockIdx.x >> 6;   // 64 tiles per batch
    const int t0   = (blockIdx.x & 63) * TB;
    const int tb0  = t0 >> 4;
    const int jl   = lane & 15;
    const int rb   = (lane >> 4) * 4;   // C/D fragment row base
    const int l1   = ((((rb + 12) & 15) >> 2) << 4) | jl;   // a1t lane (halo -4 shift)
    const int rot16 = (lane + 16) & 63;  // hoisted shuffle index

    // ---- stage x tile (rows t0-4 .. t0+75, zero outside [0,T)) as bf16 A-frags ----
    #pragma unroll
    for (int it = 0; it < 3; ++it) {
        int chunk = tid + it * 512;          // [0, 1280): mt*256 + kt*64 + l
        if (chunk < MTH * 256) {
            int mt  = chunk >> 8;
            int kt  = (chunk >> 6) & 3;
            int l   = chunk & 63;
            int row = mt * 16 + (l & 15);
            int t   = t0 - 4 + row;
            int c0  = kt * 32 + (l >> 4) * 8;
            float4 p0 = make_float4(0.f, 0.f, 0.f, 0.f), p1 = p0;
            if (t >= 0 && t < NT) {
                const float* src = &x[((size_t)b * NT + t) * NC + c0];
                p0 = *reinterpret_cast<const float4*>(src);
                p1 = *reinterpret_cast<const float4*>(src + 4);
            }
            bf16x8 s;
            s[0] = (short)f2bf(p0.x); s[1] = (short)f2bf(p0.y);
            s[2] = (short)f2bf(p0.z); s[3] = (short)f2bf(p0.w);
            s[4] = (short)f2bf(p1.x); s[5] = (short)f2bf(p1.y);
            s[6] = (short)f2bf(p1.z); s[7] = (short)f2bf(p1.w);
            *reinterpret_cast<bf16x8*>(&xs[chunk * 8]) = s;
        }
    }
    __syncthreads();

    // ---- GEMM1: h(80x512) = x @ wb; wave owns 64 cols (jt = wave*4+n) ----
    f32x4 acc1[MTH][4];
    #pragma unroll
    for (int m = 0; m < MTH; ++m)
        #pragma unroll
        for (int n = 0; n < 4; ++n)
            acc1[m][n] = (f32x4){0.f, 0.f, 0.f, 0.f};

    #pragma unroll
    for (int kt = 0; kt < 4; ++kt) {
        bf16x8 af[MTH];
        #pragma unroll
        for (int m = 0; m < MTH; ++m)
            af[m] = *reinterpret_cast<const bf16x8*>(&xs[((m * 4 + kt) * 64 + lane) * 8]);
        #pragma unroll
        for (int n = 0; n < 4; ++n) {
            int jt = wave * 4 + n;
            bf16x8 bfr = *reinterpret_cast<const bf16x8*>(&wbt[((kt * 32 + jt) * 64 + lane) * 8]);
            #pragma unroll
            for (int m = 0; m < MTH; ++m)
                acc1[m][n] = __builtin_amdgcn_mfma_f32_16x16x32_bf16(af[m], bfr, acc1[m][n], 0, 0, 0);
        }
    }

    // ---- PReLU1 (OOB rows of h are exactly 0; alpha value there irrelevant) ----
    #pragma unroll
    for (int m = 0; m < MTH; ++m) {
        #pragma unroll
        for (int n = 0; n < 4; ++n) {
            int jt = wave * 4 + n;
            if (PACKED) {
                int tt = tb0 + m - (rb == 0 ? 1 : 0);
                tt = min(max(tt, 0), NT / 16 - 1);
                bf16x4 av = *reinterpret_cast<const bf16x4*>(
                    &a1t[(((size_t)tt * 32 + jt) * 64 + l1) * 4]);
                #pragma unroll
                for (int reg = 0; reg < 4; ++reg) {
                    float al = bf2f(av[reg]);
                    float v  = acc1[m][n][reg];
                    acc1[m][n][reg] = fmaxf(v, 0.f) + al * fminf(v, 0.f);
                }
            } else {
                int j = jt * 16 + jl;
                #pragma unroll
                for (int reg = 0; reg < 4; ++reg) {
                    int t  = t0 - 4 + m * 16 + rb + reg;
                    int tc = min(max(t, 0), NT - 1);
                    float al = a1[(size_t)tc * NH + j];
                    float v  = acc1[m][n][reg];
                    acc1[m][n][reg] = fmaxf(v, 0.f) + al * fminf(v, 0.f);
                }
            }
        }
    }
    __syncthreads();   // all xs reads done; ys may now overwrite the union

    // ---- depthwise dilated conv (taps g, g+4, g+8) + PReLU2 -> ys (A-frag) ----
    // Provider-side select halves the shuffle count:
    //   tap+4: provider (group (G+1)&3) supplies acc1[m+1] iff it wrapped (lane<16)
    //   tap+8: provider (group (G+2)&3) supplies acc1[m+1] iff it wrapped (lane<32);
    //          rotate-by-32 == xor-32 (permlane-eligible, no bpermute needed)
    float kw0[4], kw1[4], kw2[4];
    #pragma unroll
    for (int n = 0; n < 4; ++n) {
        int j = wave * 64 + n * 16 + jl;
        kw0[n] = wd[0 * NH + j];
        kw1[n] = wd[1 * NH + j];
        kw2[n] = wd[2 * NH + j];
    }

    #pragma unroll
    for (int m = 0; m < MT; ++m) {
        #pragma unroll
        for (int n = 0; n < 4; ++n) {
            int j   = wave * 64 + n * 16 + jl;
            int kt2 = j >> 5;
            int l2h = ((j >> 3) & 3) << 4;
            int i2  = j & 7;
            bf16x4 av2;
            if (PACKED)
                av2 = *reinterpret_cast<const bf16x4*>(
                    &a2t[(((size_t)(tb0 + m) * 32 + (j >> 4)) * 64 + lane) * 4]);
            #pragma unroll
            for (int reg = 0; reg < 4; ++reg) {
                float vm  = acc1[m][n][reg];
                float vm1 = acc1[m + 1][n][reg];
                float p4 = (lane < 16) ? vm1 : vm;
                float p8 = (lane < 32) ? vm1 : vm;
                float h4 = __shfl(p4, rot16);
                float h8 = __shfl_xor(p8, 32);
                float v = kw0[n] * vm + kw1[n] * h4 + kw2[n] * h8;
                int g = m * 16 + rb + reg;              // output row [0,64)
                float al;
                if (PACKED) al = bf2f(av2[reg]);
                else        al = a2[(size_t)(t0 + g) * NH + j];
                v = fmaxf(v, 0.f) + al * fminf(v, 0.f);
                int l2 = (g & 15) | l2h;
                ys[((m * 16 + kt2) * 64 + l2) * 8 + i2] = (short)f2bf(v);
            }
        }
    }
    __syncthreads();

    // ---- GEMM2/3: out(64x256) = y(64x512) @ [wres|wskip]; wave owns 32 cols ----
    f32x4 acc2[MT][2];
    #pragma unroll
    for (int m = 0; m < MT; ++m)
        #pragma unroll
        for (int n = 0; n < 2; ++n)
            acc2[m][n] = (f32x4){0.f, 0.f, 0.f, 0.f};

    #pragma unroll
    for (int kt = 0; kt < 16; ++kt) {
        bf16x8 A[MT];
        #pragma unroll
        for (int m = 0; m < MT; ++m)
            A[m] = *reinterpret_cast<const bf16x8*>(&ys[((m * 16 + kt) * 64 + lane) * 8]);
        #pragma unroll
        for (int n = 0; n < 2; ++n) {
            int jt = wave * 2 + n;
            bf16x8 Bf = *reinterpret_cast<const bf16x8*>(&wct[((kt * 16 + jt) * 64 + lane) * 8]);
            #pragma unroll
            for (int m = 0; m < MT; ++m)
                acc2[m][n] = __builtin_amdgcn_mfma_f32_16x16x32_bf16(A[m], Bf, acc2[m][n], 0, 0, 0);
        }
    }

    // ---- epilogue: waves 0-3 -> residual (+x), waves 4-7 -> skip ----
    #pragma unroll
    for (int m = 0; m < MT; ++m) {
        #pragma unroll
        for (int n = 0; n < 2; ++n) {
            int j = wave * 32 + n * 16 + jl;            // [0,256), wave-uniform split
            #pragma unroll
            for (int reg = 0; reg < 4; ++reg) {
                int g = m * 16 + rb + reg;
                size_t t = (size_t)(t0 + g);
                float v = acc2[m][n][reg];
                if (j < 128) {
                    size_t idx = ((size_t)b * NT + t) * NC + j;
                    out[idx] = v + x[idx];
                } else {
                    size_t idx = ((size_t)b * NT + t) * NC + (j - 128);
                    out[(size_t)NB * NT * NC + idx] = v;
                }
            }
        }
    }
}

extern "C" void kernel_launch(void* const* d_in, const int* in_sizes, int n_in,
                              void* d_out, int out_size, void* d_ws, size_t ws_size,
                              hipStream_t stream) {
    const float* x  = (const float*)d_in[0];
    const float* wb = (const float*)d_in[1];
    const float* a1 = (const float*)d_in[2];
    const float* wd = (const float*)d_in[3];
    const float* a2 = (const float*)d_in[4];
    const float* wr = (const float*)d_in[5];
    const float* wk = (const float*)d_in[6];
    float* out = (float*)d_out;

    short* wbt = (short*)d_ws;             // 65536 bf16
    short* wct = wbt + 65536;              // 131072 bf16
    short* a1t = wct + 131072;             // 2097152 bf16
    short* a2t = a1t + 2097152;            // 2097152 bf16
    const size_t need = (size_t)(65536 + 131072 + 2 * 2097152) * 2;
    const bool packed = (ws_size >= need);
    const int nalpha = packed ? 2048 : 0;

    prep_all<<<dim3(nalpha + 384), dim3(512), 0, stream>>>(
        wb, wr, wk, a1, a2, wbt, wct, a1t, a2t, nalpha);

    if (packed) {
        conv1d_block_mfma<true><<<dim3(NB * (NT / TB)), dim3(512), 0, stream>>>(
            x, a1, wd, a2, wbt, wct, a1t, a2t, out);
    } else {
        conv1d_block_mfma<false><<<dim3(NB * (NT / TB)), dim3(512), 0, stream>>>(
            x, a1, wd, a2, wbt, wct, nullptr, nullptr, out);
    }
}

// Round 7
// 49.904 us; speedup vs baseline: 1.7038x; 1.7038x over previous
//
#include <hip/hip_runtime.h>
#include <hip/hip_bf16.h>

#define NB 8
#define NT 4096
#define NC 128
#define NH 512
#define TB 32            // output time rows per block
#define MT 2             // output m-tiles (MT*16 == TB)
#define MTH 3            // staged h m-tiles (TB + 8 halo + pad -> 48 rows)

typedef __attribute__((ext_vector_type(8))) short bf16x8;
typedef __attribute__((ext_vector_type(4))) short bf16x4;
typedef __attribute__((ext_vector_type(4))) float f32x4;

__device__ __forceinline__ ushort f2bf(float f) {
    uint u = __float_as_uint(f);
    uint r = u + 0x7FFFu + ((u >> 16) & 1u);   // RNE
    return (ushort)(r >> 16);
}
__device__ __forceinline__ float bf2f(short b) {
    return __uint_as_float(((uint)(ushort)b) << 16);
}

// ---- Merged prep: weights + alphas to bf16, MFMA-fragment order (verified R4) ----
__global__ __launch_bounds__(512) void prep_all(
    const float* __restrict__ wb, const float* __restrict__ wres,
    const float* __restrict__ wskip, const float* __restrict__ a1,
    const float* __restrict__ a2, short* __restrict__ wbt,
    short* __restrict__ wct, short* __restrict__ a1t, short* __restrict__ a2t,
    int nalpha_blocks)
{
    int blk = blockIdx.x;
    if (blk < nalpha_blocks) {
        int g = blk * 512 + threadIdx.x;                 // [0, 1048576)
        const float* __restrict__ src = (g < 524288) ? a1 : a2;
        short* __restrict__ dst = (g < 524288) ? a1t : a2t;
        int o  = g & 524287;
        int l  = o & 63, jt = (o >> 6) & 31, tt = o >> 11;
        int t  = tt * 16 + ((l >> 4) << 2);
        int j  = jt * 16 + (l & 15);
        bf16x4 v;
        #pragma unroll
        for (int r = 0; r < 4; ++r) v[r] = (short)f2bf(src[(size_t)(t + r) * NH + j]);
        *reinterpret_cast<bf16x4*>(&dst[(size_t)o * 4]) = v;
    } else {
        int i = (blk - nalpha_blocks) * 512 + threadIdx.x;   // [0, 196608)
        if (i < 65536) {
            int ii = i & 7, l = (i >> 3) & 63, jt = (i >> 9) & 31, kt = i >> 14;
            int k = kt * 32 + (l >> 4) * 8 + ii;
            int j = jt * 16 + (l & 15);
            wbt[i] = (short)f2bf(wb[k * NH + j]);
        } else if (i < 65536 + 131072) {
            int i2 = i - 65536;
            int ii = i2 & 7, l = (i2 >> 3) & 63, jt = (i2 >> 9) & 15, kt = i2 >> 13;
            int k = kt * 32 + (l >> 4) * 8 + ii;
            int j = jt * 16 + (l & 15);
            float v = (j < 128) ? wres[k * NC + j] : wskip[k * NC + (j - 128)];
            wct[i2] = (short)f2bf(v);
        }
    }
}

// ---- Fused main kernel: 512 threads (8 waves), 32-row tile, small per-wave state ----
template<bool PACKED>
__global__ __launch_bounds__(512, 4) void conv1d_block_mfma(
    const float* __restrict__ x,      // (8,4096,128)
    const float* __restrict__ a1,     // (4096,512) f32 (fallback)
    const float* __restrict__ wd,     // (3,1,512)
    const float* __restrict__ a2,     // (4096,512) f32 (fallback)
    const short* __restrict__ wbt,
    const short* __restrict__ wct,
    const short* __restrict__ a1t,    // packed alphas (PACKED)
    const short* __restrict__ a2t,
    float* __restrict__ out)
{
    // A-frag layout: frag (mt,kt): lane l elem i = M[mt*16 + (l&15)][kt*32 + (l>>4)*8 + i]
    // union: xs (48x128 bf16 A-frags, 12 KB) inside ys (32x512 bf16 A-frags, 32 KB)
    __shared__ short smem[MT * 16 * 64 * 8];   // 32 KB
    short* xs = smem;
    short* ys = smem;

    const int tid  = threadIdx.x;
    const int lane = tid & 63;
    const int wave = tid >> 6;          // 0..7
    const int b    = blockIdx.x >> 7;   // 128 tiles per batch
    const int t0   = (blockIdx.x & 127) * TB;
    const int tb0  = t0 >> 4;
    const int jl   = lane & 15;
    const int rb   = (lane >> 4) * 4;   // C/D fragment row base
    const int l1   = ((((rb + 12) & 15) >> 2) << 4) | jl;   // a1t lane (halo -4 shift)
    const int rot16 = (lane + 16) & 63;

    // ---- stage x tile (rows t0-4 .. t0+43, zero outside [0,T)) as bf16 A-frags ----
    #pragma unroll
    for (int it = 0; it < 2; ++it) {
        int chunk = tid + it * 512;          // [0, 768): mt*256 + kt*64 + l
        if (chunk < MTH * 256) {
            int mt  = chunk >> 8;
            int kt  = (chunk >> 6) & 3;
            int l   = chunk & 63;
            int row = mt * 16 + (l & 15);
            int t   = t0 - 4 + row;
            int c0  = kt * 32 + (l >> 4) * 8;
            float4 p0 = make_float4(0.f, 0.f, 0.f, 0.f), p1 = p0;
            if (t >= 0 && t < NT) {
                const float* src = &x[((size_t)b * NT + t) * NC + c0];
                p0 = *reinterpret_cast<const float4*>(src);
                p1 = *reinterpret_cast<const float4*>(src + 4);
            }
            bf16x8 s;
            s[0] = (short)f2bf(p0.x); s[1] = (short)f2bf(p0.y);
            s[2] = (short)f2bf(p0.z); s[3] = (short)f2bf(p0.w);
            s[4] = (short)f2bf(p1.x); s[5] = (short)f2bf(p1.y);
            s[6] = (short)f2bf(p1.z); s[7] = (short)f2bf(p1.w);
            *reinterpret_cast<bf16x8*>(&xs[chunk * 8]) = s;
        }
    }
    __syncthreads();

    // ---- GEMM1: h(48x512) = x @ wb; wave owns 64 cols (jt = wave*4+n, n<4) ----
    f32x4 acc1[MTH][4];
    #pragma unroll
    for (int m = 0; m < MTH; ++m)
        #pragma unroll
        for (int n = 0; n < 4; ++n)
            acc1[m][n] = (f32x4){0.f, 0.f, 0.f, 0.f};

    #pragma unroll
    for (int kt = 0; kt < 4; ++kt) {
        bf16x8 af[MTH];
        #pragma unroll
        for (int m = 0; m < MTH; ++m)
            af[m] = *reinterpret_cast<const bf16x8*>(&xs[((m * 4 + kt) * 64 + lane) * 8]);
        #pragma unroll
        for (int n = 0; n < 4; ++n) {
            int jt = wave * 4 + n;
            bf16x8 bfr = *reinterpret_cast<const bf16x8*>(&wbt[((kt * 32 + jt) * 64 + lane) * 8]);
            #pragma unroll
            for (int m = 0; m < MTH; ++m)
                acc1[m][n] = __builtin_amdgcn_mfma_f32_16x16x32_bf16(af[m], bfr, acc1[m][n], 0, 0, 0);
        }
    }

    // ---- PReLU1 (OOB rows of h are exactly 0; alpha value there irrelevant) ----
    #pragma unroll
    for (int m = 0; m < MTH; ++m) {
        #pragma unroll
        for (int n = 0; n < 4; ++n) {
            int jt = wave * 4 + n;
            if (PACKED) {
                int tt = tb0 + m - (rb == 0 ? 1 : 0);
                tt = min(max(tt, 0), NT / 16 - 1);
                bf16x4 av = *reinterpret_cast<const bf16x4*>(
                    &a1t[(((size_t)tt * 32 + jt) * 64 + l1) * 4]);
                #pragma unroll
                for (int reg = 0; reg < 4; ++reg) {
                    float al = bf2f(av[reg]);
                    float v  = acc1[m][n][reg];
                    acc1[m][n][reg] = fmaxf(v, 0.f) + al * fminf(v, 0.f);
                }
            } else {
                int j = jt * 16 + jl;
                #pragma unroll
                for (int reg = 0; reg < 4; ++reg) {
                    int t  = t0 - 4 + m * 16 + rb + reg;
                    int tc = min(max(t, 0), NT - 1);
                    float al = a1[(size_t)tc * NH + j];
                    float v  = acc1[m][n][reg];
                    acc1[m][n][reg] = fmaxf(v, 0.f) + al * fminf(v, 0.f);
                }
            }
        }
    }
    __syncthreads();   // all xs reads done; ys may now overwrite the union

    // ---- depthwise dilated conv (taps g, g+4, g+8) + PReLU2 -> ys (A-frag) ----
    // provider-select (verified R6): tap+4 = select + shfl(rot16); tap+8 = select + shfl_xor(32)
    float kw0[4], kw1[4], kw2[4];
    #pragma unroll
    for (int n = 0; n < 4; ++n) {
        int j = wave * 64 + n * 16 + jl;
        kw0[n] = wd[0 * NH + j];
        kw1[n] = wd[1 * NH + j];
        kw2[n] = wd[2 * NH + j];
    }

    #pragma unroll
    for (int m = 0; m < MT; ++m) {
        #pragma unroll
        for (int n = 0; n < 4; ++n) {
            int j   = wave * 64 + n * 16 + jl;
            int kt2 = j >> 5;
            int l2h = ((j >> 3) & 3) << 4;
            int i2  = j & 7;
            bf16x4 av2;
            if (PACKED)
                av2 = *reinterpret_cast<const bf16x4*>(
                    &a2t[(((size_t)(tb0 + m) * 32 + (j >> 4)) * 64 + lane) * 4]);
            #pragma unroll
            for (int reg = 0; reg < 4; ++reg) {
                float vm  = acc1[m][n][reg];
                float vm1 = acc1[m + 1][n][reg];
                float p4 = (lane < 16) ? vm1 : vm;
                float p8 = (lane < 32) ? vm1 : vm;
                float h4 = __shfl(p4, rot16);
                float h8 = __shfl_xor(p8, 32);
                float v = kw0[n] * vm + kw1[n] * h4 + kw2[n] * h8;
                int g = m * 16 + rb + reg;              // output row [0,32)
                float al;
                if (PACKED) al = bf2f(av2[reg]);
                else        al = a2[(size_t)(t0 + g) * NH + j];
                v = fmaxf(v, 0.f) + al * fminf(v, 0.f);
                int l2 = (g & 15) | l2h;
                ys[((m * 16 + kt2) * 64 + l2) * 8 + i2] = (short)f2bf(v);
            }
        }
    }
    __syncthreads();

    // ---- GEMM2/3: out(32x256) = y(32x512) @ [wres|wskip]; wave owns 32 cols ----
    f32x4 acc2[MT][2];
    #pragma unroll
    for (int m = 0; m < MT; ++m)
        #pragma unroll
        for (int n = 0; n < 2; ++n)
            acc2[m][n] = (f32x4){0.f, 0.f, 0.f, 0.f};

    #pragma unroll
    for (int kt = 0; kt < 16; ++kt) {
        bf16x8 A[MT];
        #pragma unroll
        for (int m = 0; m < MT; ++m)
            A[m] = *reinterpret_cast<const bf16x8*>(&ys[((m * 16 + kt) * 64 + lane) * 8]);
        #pragma unroll
        for (int n = 0; n < 2; ++n) {
            int jt = wave * 2 + n;
            bf16x8 Bf = *reinterpret_cast<const bf16x8*>(&wct[((kt * 16 + jt) * 64 + lane) * 8]);
            #pragma unroll
            for (int m = 0; m < MT; ++m)
                acc2[m][n] = __builtin_amdgcn_mfma_f32_16x16x32_bf16(A[m], Bf, acc2[m][n], 0, 0, 0);
        }
    }

    // ---- epilogue: waves 0-3 -> residual (+x), waves 4-7 -> skip ----
    #pragma unroll
    for (int m = 0; m < MT; ++m) {
        #pragma unroll
        for (int n = 0; n < 2; ++n) {
            int j = wave * 32 + n * 16 + jl;            // [0,256), wave-uniform split
            #pragma unroll
            for (int reg = 0; reg < 4; ++reg) {
                int g = m * 16 + rb + reg;
                size_t t = (size_t)(t0 + g);
                float v = acc2[m][n][reg];
                if (j < 128) {
                    size_t idx = ((size_t)b * NT + t) * NC + j;
                    out[idx] = v + x[idx];
                } else {
                    size_t idx = ((size_t)b * NT + t) * NC + (j - 128);
                    out[(size_t)NB * NT * NC + idx] = v;
                }
            }
        }
    }
}

extern "C" void kernel_launch(void* const* d_in, const int* in_sizes, int n_in,
                              void* d_out, int out_size, void* d_ws, size_t ws_size,
                              hipStream_t stream) {
    const float* x  = (const float*)d_in[0];
    const float* wb = (const float*)d_in[1];
    const float* a1 = (const float*)d_in[2];
    const float* wd = (const float*)d_in[3];
    const float* a2 = (const float*)d_in[4];
    const float* wr = (const float*)d_in[5];
    const float* wk = (const float*)d_in[6];
    float* out = (float*)d_out;

    short* wbt = (short*)d_ws;             // 65536 bf16
    short* wct = wbt + 65536;              // 131072 bf16
    short* a1t = wct + 131072;             // 2097152 bf16
    short* a2t = a1t + 2097152;            // 2097152 bf16
    const size_t need = (size_t)(65536 + 131072 + 2 * 2097152) * 2;
    const bool packed = (ws_size >= need);
    const int nalpha = packed ? 2048 : 0;

    prep_all<<<dim3(nalpha + 384), dim3(512), 0, stream>>>(
        wb, wr, wk, a1, a2, wbt, wct, a1t, a2t, nalpha);

    if (packed) {
        conv1d_block_mfma<true><<<dim3(NB * (NT / TB)), dim3(512), 0, stream>>>(
            x, a1, wd, a2, wbt, wct, a1t, a2t, out);
    } else {
        conv1d_block_mfma<false><<<dim3(NB * (NT / TB)), dim3(512), 0, stream>>>(
            x, a1, wd, a2, wbt, wct, nullptr, nullptr, out);
    }
}